// Round 7
// baseline (202.783 us; speedup 1.0000x reference)
//
#include <hip/hip_runtime.h>
#include <stdint.h>

#define BS 4
#define SEQ 1024
#define DIM 1024
#define NH 16
#define DH 64
#define MROWS (BS*SEQ)   // 4096

#define MT 128
#define NT 64
#define KT 32
#define NBM (MROWS/MT)   // 32
#define NBN (DIM/NT)     // 16
#define NWG (NBM*NBN)    // 512
#define NKT (DIM/KT)     // 32

typedef __attribute__((ext_vector_type(8))) short bf16x8;
typedef __attribute__((ext_vector_type(4))) float f32x4;
typedef __attribute__((ext_vector_type(8))) unsigned short ushort8;
typedef __attribute__((ext_vector_type(4))) float float4v;
typedef __attribute__((ext_vector_type(4))) int int4v;
typedef __attribute__((ext_vector_type(2))) unsigned int uint32x2;

__device__ __forceinline__ unsigned short f2bf(float x) {
  union { float f; uint32_t u; } a; a.f = x;
  uint32_t r = (a.u + 0x7FFFu + ((a.u >> 16) & 1u)) >> 16;  // RNE
  return (unsigned short)r;
}

// packed f32x2 -> bf16x2 (lo = first arg); no builtin on gfx950 -> inline asm (T12)
__device__ __forceinline__ uint32_t cvtpk_bf16(float lo, float hi) {
  uint32_t d;
  asm("v_cvt_pk_bf16_f32 %0, %1, %2" : "=v"(d) : "v"(lo), "v"(hi));
  return d;
}

typedef const void __attribute__((address_space(1)))* gvp;
typedef void __attribute__((address_space(3)))* lvp;
__device__ __forceinline__ void gld_lds16(const void* g, void* l) {
  // async global->LDS, 16B/lane; LDS dest = wave-uniform base + lane*16
  __builtin_amdgcn_global_load_lds((gvp)g, (lvp)l, 16, 0, 0);
}

// ---------------- fp32 -> bf16 cast (query/key/value) ----------------
__global__ __launch_bounds__(256) void cast_qkv(
    const float* __restrict__ q, const float* __restrict__ k, const float* __restrict__ v,
    unsigned short* __restrict__ qo, unsigned short* __restrict__ ko, unsigned short* __restrict__ vo) {
  const float* s = blockIdx.y == 0 ? q : (blockIdx.y == 1 ? k : v);
  unsigned short* d = blockIdx.y == 0 ? qo : (blockIdx.y == 1 ? ko : vo);
  size_t i = ((size_t)blockIdx.x * 256 + threadIdx.x) * 8;
  float4v x0 = *(const float4v*)(s + i);
  float4v x1 = *(const float4v*)(s + i + 4);
  ushort8 r;
  r[0]=f2bf(x0[0]); r[1]=f2bf(x0[1]); r[2]=f2bf(x0[2]); r[3]=f2bf(x0[3]);
  r[4]=f2bf(x1[0]); r[5]=f2bf(x1[1]); r[6]=f2bf(x1[2]); r[7]=f2bf(x1[3]);
  *(ushort8*)(d + i) = r;
}

// ---------------- weight cast + transpose: WT[n][k] = bf16(W[k][n]) ----------------
__global__ __launch_bounds__(256) void wcast_t(
    const float* __restrict__ w0, const float* __restrict__ w1,
    const float* __restrict__ w2, const float* __restrict__ w3,
    unsigned short* __restrict__ t0, unsigned short* __restrict__ t1,
    unsigned short* __restrict__ t2, unsigned short* __restrict__ t3) {
  __shared__ float tile[32][33];
  const float* W = blockIdx.z == 0 ? w0 : blockIdx.z == 1 ? w1 : blockIdx.z == 2 ? w2 : w3;
  unsigned short* T = blockIdx.z == 0 ? t0 : blockIdx.z == 1 ? t1 : blockIdx.z == 2 ? t2 : t3;
  int tx = threadIdx.x & 31, ty = threadIdx.x >> 5;   // 32 x 8
  int bx = blockIdx.x, by = blockIdx.y;
#pragma unroll
  for (int j = 0; j < 4; j++)
    tile[ty + 8*j][tx] = W[(size_t)(by*32 + ty + 8*j)*DIM + bx*32 + tx];
  __syncthreads();
#pragma unroll
  for (int j = 0; j < 4; j++)
    T[(size_t)(bx*32 + ty + 8*j)*DIM + by*32 + tx] = f2bf(tile[tx][ty + 8*j]);
}

// ---------------- GEMM core: C[M=4096,N=1024] = A @ BT^T (+bias) ----------------
// MODE 0: bf16 out, (acc+bias)*scale, natural [row][col]
// MODE 2: bf16 out, acc+bias, written transposed per head: VT[b][h][d][s]
// MODE 3: f32 out, acc+bias
template<int MODE>
__device__ __forceinline__ void gemm_core(
    unsigned short* lds,
    const unsigned short* __restrict__ A, const unsigned short* __restrict__ BT,
    const float* __restrict__ bias, void* __restrict__ outp, float scale) {
  unsigned short* Abase = lds;                 // 2 x MT*KT
  unsigned short* Bbase = lds + 2*MT*KT;       // 2 x NT*KT
  int id = blockIdx.x;
  int sw = (id & 7) * (NWG/8) + (id >> 3);     // XCD-aware swizzle (bijective, 512%8==0)
  int bm = sw & (NBM-1), bn = sw >> 5;
  int tid = threadIdx.x, w = tid >> 6, l = tid & 63;
  int wr = w >> 1, wc = w & 1;
  int lr = l & 15, lg = l >> 4;

  auto stage = [&](int buf, int kt) {
    const unsigned short* a0 = A + (size_t)(bm*MT + w*32 + (l>>2))*DIM + kt*KT + (l&3)*8;
    gld_lds16(a0,          Abase + buf*MT*KT + (w*32)*KT);
    gld_lds16(a0 + 16*DIM, Abase + buf*MT*KT + (w*32 + 16)*KT);
    const unsigned short* b0 = BT + (size_t)(bn*NT + w*16 + (l>>2))*DIM + kt*KT + (l&3)*8;
    gld_lds16(b0,          Bbase + buf*NT*KT + (w*16)*KT);
  };

  f32x4 acc[4][2] = {};
  int buf = 0;
  stage(0, 0);
  __syncthreads();
  for (int kt = 0; kt < NKT; kt++) {
    if (kt + 1 < NKT) stage(buf ^ 1, kt + 1);
    unsigned short* As = Abase + buf*MT*KT;
    unsigned short* Bs = Bbase + buf*NT*KT;
    bf16x8 af[4], bf_[2];
#pragma unroll
    for (int mi = 0; mi < 4; mi++)
      af[mi] = *(const bf16x8*)&As[(wr*64 + mi*16 + lr)*KT + lg*8];
#pragma unroll
    for (int ni = 0; ni < 2; ni++)
      bf_[ni] = *(const bf16x8*)&Bs[(wc*32 + ni*16 + lr)*KT + lg*8];
#pragma unroll
    for (int mi = 0; mi < 4; mi++)
#pragma unroll
      for (int ni = 0; ni < 2; ni++)
        acc[mi][ni] = __builtin_amdgcn_mfma_f32_16x16x32_bf16(af[mi], bf_[ni], acc[mi][ni], 0, 0, 0);
    __syncthreads();   // drains vmcnt for the staged next tile + protects buffer reuse
    buf ^= 1;
  }

  int row0 = bm*MT + wr*64;
  int col0 = bn*NT + wc*32;
#pragma unroll
  for (int ni = 0; ni < 2; ni++) {
    int col = col0 + ni*16 + lr;
    float bv = bias[col];
#pragma unroll
    for (int mi = 0; mi < 4; mi++)
#pragma unroll
      for (int r = 0; r < 4; r++) {
        int row = row0 + mi*16 + lg*4 + r;
        float val = acc[mi][ni][r] + bv;
        if (MODE == 0) {
          ((unsigned short*)outp)[(size_t)row*DIM + col] = f2bf(val * scale);
        } else if (MODE == 2) {
          int b = row >> 10, s = row & 1023, h = col >> 6, d = col & 63;
          ((unsigned short*)outp)[(size_t)((b*NH + h)*DH + d)*SEQ + s] = f2bf(val);
        } else {
          ((float*)outp)[(size_t)row*DIM + col] = val;
        }
      }
  }
}

__global__ __launch_bounds__(256) void qkv_gemm(
    const unsigned short* __restrict__ qb, const unsigned short* __restrict__ kb,
    const unsigned short* __restrict__ vb,
    const unsigned short* __restrict__ WqT, const unsigned short* __restrict__ WkT,
    const unsigned short* __restrict__ WvT,
    const float* __restrict__ bq, const float* __restrict__ bk, const float* __restrict__ bv,
    unsigned short* __restrict__ Qp, unsigned short* __restrict__ Kp,
    unsigned short* __restrict__ VT) {
  __shared__ __align__(16) unsigned short lds[2*(MT+NT)*KT];
  int z = blockIdx.y;
  if (z == 0)      gemm_core<0>(lds, qb, WqT, bq, Qp, 0.125f);   // 1/sqrt(64)
  else if (z == 1) gemm_core<0>(lds, kb, WkT, bk, Kp, 1.0f);
  else             gemm_core<2>(lds, vb, WvT, bv, VT, 1.0f);
}

__global__ __launch_bounds__(256) void out_gemm(
    const unsigned short* __restrict__ ctx, const unsigned short* __restrict__ WoT,
    const float* __restrict__ bo, float* __restrict__ out) {
  __shared__ __align__(16) unsigned short lds[2*(MT+NT)*KT];
  gemm_core<3>(lds, ctx, WoT, bo, out, 1.0f);
}

// ---------------- flash attention, barrier-free (independent waves) ----------------
// grid 1024, head-major (bh = blk&63): all 16 q-tile blocks of a head co-locate
// per XCD -> K+V (256KB/head) are L2-resident, so K is loaded DIRECT from global
// (guide Common-mistake #7: LDS-staging L2-fit data is pure overhead). No K LDS,
// NO in-loop __syncthreads: each wave owns its q-tile + private P slab + per-lane
// softmax state; waves drift freely and hide each other's latency (m191 regime ->
// s_setprio(1) around MFMA pays). Swapped QK^T: S^T = mfma(K,Q), lane owns q-row
// lr; max/sum reduce = 2 shfl each; tree-fmax (depth 4 vs 15-serial chain).
__global__ __launch_bounds__(256, 4) void attn(
    const unsigned short* __restrict__ Qp, const unsigned short* __restrict__ Kp,
    const unsigned short* __restrict__ VT, const int* __restrict__ mask,
    const float* __restrict__ gauss, unsigned short* __restrict__ ctx) {
  __shared__ __align__(16) unsigned short P[4][16][72];   // per-wave slab, padded
  __shared__ float gwl[SEQ];                              // mask-folded gauss weights
  int blk = blockIdx.x;
  int bh = blk & 63, qt = blk >> 6;        // head-major: head bh pinned to XCD bh%8
  int b = bh >> 4, h = bh & 15;
  int tid = threadIdx.x, w = tid >> 6, l = tid & 63;
  int lr = l & 15, lg = l >> 4;
  int q0 = qt*64 + w*16;

  // ---- stash mask-folded gauss row in LDS (once; single barrier of the kernel) ----
  {
    int i4 = tid * 4;
    float4v g4 = *(const float4v*)(gauss + b*SEQ + i4);
    int4v   m4 = *(const int4v*)(mask + b*SEQ + i4);
#pragma unroll
    for (int j = 0; j < 4; j++) gwl[i4 + j] = m4[j] ? g4[j] + 1e-10f : 0.f;
  }
  __syncthreads();

  const unsigned short* Qb = Qp + (size_t)(b*SEQ + q0 + lr)*DIM + h*DH + lg*8;
  bf16x8 aq0 = *(const bf16x8*)Qb;
  bf16x8 aq1 = *(const bf16x8*)(Qb + 32);

  float m_ = -1e30f, l_ = 0.f;             // per-lane scalars (q = lr)
  f32x4 cacc[4] = {};                      // O^T[d = dt*16+lg*4+r][q = lr]

  const unsigned short* Kb  = Kp + (size_t)(b*SEQ + lr)*DIM + h*DH + lg*8;  // + key*DIM
  const unsigned short* Vb0 = VT + (size_t)((b*NH + h)*DH + lr)*SEQ + lg*8;

  for (int kt = 0; kt < 16; kt++) {
    int key0 = kt*64;
    // ---- K fragments direct from global (L2-hot; same values as swizzled-LDS path) ----
    bf16x8 kf[4][2];
#pragma unroll
    for (int nf = 0; nf < 4; nf++) {
      kf[nf][0] = *(const bf16x8*)(Kb + (size_t)(key0 + nf*16)*DIM);
      kf[nf][1] = *(const bf16x8*)(Kb + (size_t)(key0 + nf*16)*DIM + 32);
    }
    // ---- V loads issued early (consumed after softmax) ----
    bf16x8 vf[4][2];
#pragma unroll
    for (int dt = 0; dt < 4; dt++) {
      vf[dt][0] = *(const bf16x8*)(Vb0 + (size_t)(dt*16)*SEQ + key0);
      vf[dt][1] = *(const bf16x8*)(Vb0 + (size_t)(dt*16)*SEQ + key0 + 32);
    }
    // ---- S^T = mfma(K, Q): sa[nf][r] = S[key = nf*16 + lg*4 + r][q = lr] ----
    f32x4 sa[4] = {};
    __builtin_amdgcn_s_setprio(1);
#pragma unroll
    for (int nf = 0; nf < 4; nf++) {
      sa[nf] = __builtin_amdgcn_mfma_f32_16x16x32_bf16(kf[nf][0], aq0, sa[nf], 0, 0, 0);
      sa[nf] = __builtin_amdgcn_mfma_f32_16x16x32_bf16(kf[nf][1], aq1, sa[nf], 0, 0, 0);
    }
    __builtin_amdgcn_s_setprio(0);
    // ---- online softmax, per-lane scalar state; tree max (depth 4) ----
    float t0 = fmaxf(fmaxf(sa[0][0], sa[0][1]), fmaxf(sa[0][2], sa[0][3]));
    float t1 = fmaxf(fmaxf(sa[1][0], sa[1][1]), fmaxf(sa[1][2], sa[1][3]));
    float t2 = fmaxf(fmaxf(sa[2][0], sa[2][1]), fmaxf(sa[2][2], sa[2][3]));
    float t3 = fmaxf(fmaxf(sa[3][0], sa[3][1]), fmaxf(sa[3][2], sa[3][3]));
    float mx = fmaxf(fmaxf(t0, t1), fmaxf(t2, t3));
    mx = fmaxf(mx, __shfl_xor(mx, 16));
    mx = fmaxf(mx, __shfl_xor(mx, 32));
    float mn = fmaxf(m_, mx);
    float alpha = __expf(m_ - mn);
    m_ = mn;
    float rsn[4];
    uint32_t u[4][2];
#pragma unroll
    for (int nf = 0; nf < 4; nf++) {
      float4v g = *(const float4v*)&gwl[key0 + nf*16 + lg*4];   // broadcast LDS read
      float p0 = __expf(sa[nf][0] - m_) * g[0];
      float p1 = __expf(sa[nf][1] - m_) * g[1];
      float p2 = __expf(sa[nf][2] - m_) * g[2];
      float p3 = __expf(sa[nf][3] - m_) * g[3];
      rsn[nf] = (p0 + p1) + (p2 + p3);
      u[nf][0] = cvtpk_bf16(p0, p1);
      u[nf][1] = cvtpk_bf16(p2, p3);
    }
    float rs = (rsn[0] + rsn[1]) + (rsn[2] + rsn[3]);
    rs += __shfl_xor(rs, 16);
    rs += __shfl_xor(rs, 32);
    l_ = l_*alpha + rs;
#pragma unroll
    for (int dt = 0; dt < 4; dt++)
#pragma unroll
      for (int r = 0; r < 4; r++) cacc[dt][r] *= alpha;
    // ---- P[q=lr][key]: 4x ds_write_b64 (wave-local slab, no cross-wave sync) ----
#pragma unroll
    for (int nf = 0; nf < 4; nf++) {
      uint32x2 uu; uu[0] = u[nf][0]; uu[1] = u[nf][1];
      *(uint32x2*)&P[w][lr][nf*16 + lg*4] = uu;
    }
    asm volatile("s_waitcnt lgkmcnt(0)" ::: "memory");
    __builtin_amdgcn_sched_barrier(0);
    bf16x8 ap0 = *(const bf16x8*)&P[w][lr][lg*8];        // B-frag: keys 0..31
    bf16x8 ap1 = *(const bf16x8*)&P[w][lr][32 + lg*8];   // B-frag: keys 32..63
    // ---- O^T += mfma(V^T, P) ----
    __builtin_amdgcn_s_setprio(1);
#pragma unroll
    for (int dt = 0; dt < 4; dt++) {
      cacc[dt] = __builtin_amdgcn_mfma_f32_16x16x32_bf16(vf[dt][0], ap0, cacc[dt], 0, 0, 0);
      cacc[dt] = __builtin_amdgcn_mfma_f32_16x16x32_bf16(vf[dt][1], ap1, cacc[dt], 0, 0, 0);
    }
    __builtin_amdgcn_s_setprio(0);
  }

  // ---- epilogue: normalize, pack pairs, 4x b64 stores per lane ----
  float inv = 1.0f / l_;
  size_t row = (size_t)(b*SEQ + q0 + lr)*DIM + h*DH;
#pragma unroll
  for (int dt = 0; dt < 4; dt++) {
    uint32x2 e;
    e[0] = cvtpk_bf16(cacc[dt][0]*inv, cacc[dt][1]*inv);
    e[1] = cvtpk_bf16(cacc[dt][2]*inv, cacc[dt][3]*inv);
    *(uint32x2*)&ctx[row + dt*16 + lg*4] = e;
  }
}

// ---------------- launch ----------------
extern "C" void kernel_launch(void* const* d_in, const int* in_sizes, int n_in,
                              void* d_out, int out_size, void* d_ws, size_t ws_size,
                              hipStream_t stream) {
  const float* query = (const float*)d_in[0];
  const float* key   = (const float*)d_in[1];
  const float* value = (const float*)d_in[2];
  const int*   mask  = (const int*)d_in[3];
  const float* gauss = (const float*)d_in[4];
  const float* Wq = (const float*)d_in[5];
  const float* bq = (const float*)d_in[6];
  const float* Wk = (const float*)d_in[7];
  const float* bk = (const float*)d_in[8];
  const float* Wv = (const float*)d_in[9];
  const float* bv = (const float*)d_in[10];
  const float* Wo = (const float*)d_in[11];
  const float* bo = (const float*)d_in[12];

  char* ws = (char*)d_ws;
  const size_t MB = 1024*1024;
  unsigned short* qb  = (unsigned short*)(ws + 0*MB);   // bf16 casts of inputs (8MB each)
  unsigned short* kb  = (unsigned short*)(ws + 8*MB);
  unsigned short* vb  = (unsigned short*)(ws + 16*MB);
  unsigned short* WqT = (unsigned short*)(ws + 24*MB);  // transposed bf16 weights (2MB each)
  unsigned short* WkT = (unsigned short*)(ws + 26*MB);
  unsigned short* WvT = (unsigned short*)(ws + 28*MB);
  unsigned short* WoT = (unsigned short*)(ws + 30*MB);
  unsigned short* Qp  = (unsigned short*)(ws + 32*MB);  // projected Q (scaled), natural layout
  unsigned short* Kp  = (unsigned short*)(ws + 40*MB);  // projected K, natural layout
  unsigned short* VTb = (unsigned short*)(ws + 48*MB);  // projected V, [b][h][d][s]
  unsigned short* ctx = (unsigned short*)(ws + 56*MB);  // attention output, natural layout

  cast_qkv<<<dim3((BS*SEQ*DIM)/(256*8), 3), 256, 0, stream>>>(query, key, value, qb, kb, vb);
  wcast_t<<<dim3(DIM/32, DIM/32, 4), 256, 0, stream>>>(Wq, Wk, Wv, Wo, WqT, WkT, WvT, WoT);
  qkv_gemm<<<dim3(NWG, 3), 256, 0, stream>>>(qb, kb, vb, WqT, WkT, WvT, bq, bk, bv, Qp, Kp, VTb);
  attn<<<BS*NH*(SEQ/64), 256, 0, stream>>>(Qp, Kp, VTb, mask, gauss, ctx);
  out_gemm<<<NWG, 256, 0, stream>>>(ctx, WoT, bo, (float*)d_out);
}

// Round 8
// 157.204 us; speedup vs baseline: 1.2899x; 1.2899x over previous
//
#include <hip/hip_runtime.h>
#include <stdint.h>

#define BS 4
#define SEQ 1024
#define DIM 1024
#define NH 16
#define DH 64
#define MROWS (BS*SEQ)   // 4096

#define MT 128
#define NT 64
#define KT 32
#define NBM (MROWS/MT)   // 32
#define NBN (DIM/NT)     // 16
#define NWG (NBM*NBN)    // 512
#define NKT (DIM/KT)     // 32

typedef __attribute__((ext_vector_type(8))) short bf16x8;
typedef __attribute__((ext_vector_type(4))) float f32x4;
typedef __attribute__((ext_vector_type(8))) unsigned short ushort8;
typedef __attribute__((ext_vector_type(4))) float float4v;
typedef __attribute__((ext_vector_type(4))) int int4v;
typedef __attribute__((ext_vector_type(2))) unsigned int uint32x2;

__device__ __forceinline__ unsigned short f2bf(float x) {
  union { float f; uint32_t u; } a; a.f = x;
  uint32_t r = (a.u + 0x7FFFu + ((a.u >> 16) & 1u)) >> 16;  // RNE
  return (unsigned short)r;
}

// packed f32x2 -> bf16x2 (lo = first arg); no builtin on gfx950 -> inline asm (T12)
__device__ __forceinline__ uint32_t cvtpk_bf16(float lo, float hi) {
  uint32_t d;
  asm("v_cvt_pk_bf16_f32 %0, %1, %2" : "=v"(d) : "v"(lo), "v"(hi));
  return d;
}

// raw 2^x (softmax runs in log2 domain; log2e folded into Q scale upstream)
__device__ __forceinline__ float exp2a(float x) {
  float r;
  asm("v_exp_f32 %0, %1" : "=v"(r) : "v"(x));
  return r;
}

// forced-early global load: asm volatile cannot be sunk to its use by the
// scheduler (R4/R5/R7 post-mortems: C-level prefetch ALWAYS sinks at hipcc's
// chosen VGPR target). Result regs stay live from issue to consumption; the
// consumer must be fenced by an explicit s_waitcnt vmcnt + sched_barrier.
__device__ __forceinline__ bf16x8 gload16(const unsigned short* p) {
  bf16x8 r;
  asm volatile("global_load_dwordx4 %0, %1, off" : "=v"(r) : "v"(p));
  return r;
}

typedef const void __attribute__((address_space(1)))* gvp;
typedef void __attribute__((address_space(3)))* lvp;
__device__ __forceinline__ void gld_lds16(const void* g, void* l) {
  // async global->LDS, 16B/lane; LDS dest = wave-uniform base + lane*16
  __builtin_amdgcn_global_load_lds((gvp)g, (lvp)l, 16, 0, 0);
}

// ---------------- fp32 -> bf16 cast (query/key/value) ----------------
__global__ __launch_bounds__(256) void cast_qkv(
    const float* __restrict__ q, const float* __restrict__ k, const float* __restrict__ v,
    unsigned short* __restrict__ qo, unsigned short* __restrict__ ko, unsigned short* __restrict__ vo) {
  const float* s = blockIdx.y == 0 ? q : (blockIdx.y == 1 ? k : v);
  unsigned short* d = blockIdx.y == 0 ? qo : (blockIdx.y == 1 ? ko : vo);
  size_t i = ((size_t)blockIdx.x * 256 + threadIdx.x) * 8;
  float4v x0 = *(const float4v*)(s + i);
  float4v x1 = *(const float4v*)(s + i + 4);
  ushort8 r;
  r[0]=f2bf(x0[0]); r[1]=f2bf(x0[1]); r[2]=f2bf(x0[2]); r[3]=f2bf(x0[3]);
  r[4]=f2bf(x1[0]); r[5]=f2bf(x1[1]); r[6]=f2bf(x1[2]); r[7]=f2bf(x1[3]);
  *(ushort8*)(d + i) = r;
}

// ---------------- weight cast + transpose: WT[n][k] = bf16(W[k][n]) ----------------
__global__ __launch_bounds__(256) void wcast_t(
    const float* __restrict__ w0, const float* __restrict__ w1,
    const float* __restrict__ w2, const float* __restrict__ w3,
    unsigned short* __restrict__ t0, unsigned short* __restrict__ t1,
    unsigned short* __restrict__ t2, unsigned short* __restrict__ t3) {
  __shared__ float tile[32][33];
  const float* W = blockIdx.z == 0 ? w0 : blockIdx.z == 1 ? w1 : blockIdx.z == 2 ? w2 : w3;
  unsigned short* T = blockIdx.z == 0 ? t0 : blockIdx.z == 1 ? t1 : blockIdx.z == 2 ? t2 : t3;
  int tx = threadIdx.x & 31, ty = threadIdx.x >> 5;   // 32 x 8
  int bx = blockIdx.x, by = blockIdx.y;
#pragma unroll
  for (int j = 0; j < 4; j++)
    tile[ty + 8*j][tx] = W[(size_t)(by*32 + ty + 8*j)*DIM + bx*32 + tx];
  __syncthreads();
#pragma unroll
  for (int j = 0; j < 4; j++)
    T[(size_t)(bx*32 + ty + 8*j)*DIM + by*32 + tx] = f2bf(tile[tx][ty + 8*j]);
}

// ---------------- GEMM core: C[M=4096,N=1024] = A @ BT^T (+bias) ----------------
// MODE 0: bf16 out, (acc+bias)*scale, natural [row][col]
// MODE 2: bf16 out, acc+bias, written transposed per head: VT[b][h][d][s]
// MODE 3: f32 out, acc+bias
template<int MODE>
__device__ __forceinline__ void gemm_core(
    unsigned short* lds,
    const unsigned short* __restrict__ A, const unsigned short* __restrict__ BT,
    const float* __restrict__ bias, void* __restrict__ outp, float scale) {
  unsigned short* Abase = lds;                 // 2 x MT*KT
  unsigned short* Bbase = lds + 2*MT*KT;       // 2 x NT*KT
  int id = blockIdx.x;
  int sw = (id & 7) * (NWG/8) + (id >> 3);     // XCD-aware swizzle (bijective, 512%8==0)
  int bm = sw & (NBM-1), bn = sw >> 5;
  int tid = threadIdx.x, w = tid >> 6, l = tid & 63;
  int wr = w >> 1, wc = w & 1;
  int lr = l & 15, lg = l >> 4;

  auto stage = [&](int buf, int kt) {
    const unsigned short* a0 = A + (size_t)(bm*MT + w*32 + (l>>2))*DIM + kt*KT + (l&3)*8;
    gld_lds16(a0,          Abase + buf*MT*KT + (w*32)*KT);
    gld_lds16(a0 + 16*DIM, Abase + buf*MT*KT + (w*32 + 16)*KT);
    const unsigned short* b0 = BT + (size_t)(bn*NT + w*16 + (l>>2))*DIM + kt*KT + (l&3)*8;
    gld_lds16(b0,          Bbase + buf*NT*KT + (w*16)*KT);
  };

  f32x4 acc[4][2] = {};
  int buf = 0;
  stage(0, 0);
  __syncthreads();
  for (int kt = 0; kt < NKT; kt++) {
    if (kt + 1 < NKT) stage(buf ^ 1, kt + 1);
    unsigned short* As = Abase + buf*MT*KT;
    unsigned short* Bs = Bbase + buf*NT*KT;
    bf16x8 af[4], bf_[2];
#pragma unroll
    for (int mi = 0; mi < 4; mi++)
      af[mi] = *(const bf16x8*)&As[(wr*64 + mi*16 + lr)*KT + lg*8];
#pragma unroll
    for (int ni = 0; ni < 2; ni++)
      bf_[ni] = *(const bf16x8*)&Bs[(wc*32 + ni*16 + lr)*KT + lg*8];
#pragma unroll
    for (int mi = 0; mi < 4; mi++)
#pragma unroll
      for (int ni = 0; ni < 2; ni++)
        acc[mi][ni] = __builtin_amdgcn_mfma_f32_16x16x32_bf16(af[mi], bf_[ni], acc[mi][ni], 0, 0, 0);
    __syncthreads();   // drains vmcnt for the staged next tile + protects buffer reuse
    buf ^= 1;
  }

  int row0 = bm*MT + wr*64;
  int col0 = bn*NT + wc*32;
#pragma unroll
  for (int ni = 0; ni < 2; ni++) {
    int col = col0 + ni*16 + lr;
    float bv = bias[col];
#pragma unroll
    for (int mi = 0; mi < 4; mi++)
#pragma unroll
      for (int r = 0; r < 4; r++) {
        int row = row0 + mi*16 + lg*4 + r;
        float val = acc[mi][ni][r] + bv;
        if (MODE == 0) {
          ((unsigned short*)outp)[(size_t)row*DIM + col] = f2bf(val * scale);
        } else if (MODE == 2) {
          int b = row >> 10, s = row & 1023, h = col >> 6, d = col & 63;
          ((unsigned short*)outp)[(size_t)((b*NH + h)*DH + d)*SEQ + s] = f2bf(val);
        } else {
          ((float*)outp)[(size_t)row*DIM + col] = val;
        }
      }
  }
}

__global__ __launch_bounds__(256) void qkv_gemm(
    const unsigned short* __restrict__ qb, const unsigned short* __restrict__ kb,
    const unsigned short* __restrict__ vb,
    const unsigned short* __restrict__ WqT, const unsigned short* __restrict__ WkT,
    const unsigned short* __restrict__ WvT,
    const float* __restrict__ bq, const float* __restrict__ bk, const float* __restrict__ bv,
    unsigned short* __restrict__ Qp, unsigned short* __restrict__ Kp,
    unsigned short* __restrict__ VT) {
  __shared__ __align__(16) unsigned short lds[2*(MT+NT)*KT];
  int z = blockIdx.y;
  // Q scale = 1/sqrt(64) * log2(e): softmax runs in exp2 domain downstream
  if (z == 0)      gemm_core<0>(lds, qb, WqT, bq, Qp, 0.18033688011112042f);
  else if (z == 1) gemm_core<0>(lds, kb, WkT, bk, Kp, 1.0f);
  else             gemm_core<2>(lds, vb, WvT, bv, VT, 1.0f);
}

__global__ __launch_bounds__(256) void out_gemm(
    const unsigned short* __restrict__ ctx, const unsigned short* __restrict__ WoT,
    const float* __restrict__ bo, float* __restrict__ out) {
  __shared__ __align__(16) unsigned short lds[2*(MT+NT)*KT];
  gemm_core<3>(lds, ctx, WoT, bo, out, 1.0f);
}

// ---------------- flash attention (R6 structure + forced-early V loads) ----------------
// grid 1024, head-major (bh = blk&63): K+V L2-resident per XCD. 4 waves x 16 q-rows.
// K: async global_load_lds double-buffer (zero-VGPR prefetch, one full iter of
// cover; drained by end-of-iter __syncthreads) with XOR-swizzled layout.
// V: asm-volatile global_load_dwordx4 issued at iter TOP (cannot be sunk by the
// scheduler, unlike C loads - R4/R5/R7 lesson), fenced by vmcnt(0)+sched_barrier
// just before PV; QK^T+softmax (~600-800cyc) covers the L2 latency.
// Swapped QK^T: lane owns q-row lr -> per-lane scalar softmax, 2 shfl per reduce.
// exp2 domain (log2e folded into Q scale): raw v_exp_f32, no per-exp multiply.
__global__ __launch_bounds__(256, 4) void attn(
    const unsigned short* __restrict__ Qp, const unsigned short* __restrict__ Kp,
    const unsigned short* __restrict__ VT, const int* __restrict__ mask,
    const float* __restrict__ gauss, unsigned short* __restrict__ ctx) {
  __shared__ __align__(16) unsigned short Klds[2*64*64];  // 16KB double-buffered K tile
  __shared__ __align__(16) unsigned short P[4][16][72];   // per-wave slab, padded
  __shared__ float gwl[SEQ];                              // mask-folded gauss weights
  int blk = blockIdx.x;
  int bh = blk & 63, qt = blk >> 6;        // head-major: head bh pinned to XCD bh%8
  int b = bh >> 4, h = bh & 15;
  int tid = threadIdx.x, w = tid >> 6, l = tid & 63;
  int lr = l & 15, lg = l >> 4;
  int q0 = qt*64 + w*16;

  // ---- stash mask-folded gauss row in LDS (once) ----
  {
    int i4 = tid * 4;
    float4v g4 = *(const float4v*)(gauss + b*SEQ + i4);
    int4v   m4 = *(const int4v*)(mask + b*SEQ + i4);
#pragma unroll
    for (int j = 0; j < 4; j++) gwl[i4 + j] = m4[j] ? g4[j] + 1e-10f : 0.f;
  }

  const unsigned short* Qb = Qp + (size_t)(b*SEQ + q0 + lr)*DIM + h*DH + lg*8;
  bf16x8 aq0 = *(const bf16x8*)Qb;
  bf16x8 aq1 = *(const bf16x8*)(Qb + 32);

  float m_ = -1e30f, l_ = 0.f;             // per-lane scalars (q = lr)
  f32x4 cacc[4] = {};                      // O^T[d = dt*16+lg*4+r][q = lr]

  const unsigned short* Krow0 = Kp + (size_t)(b*SEQ)*DIM + h*DH;
  const unsigned short* Vb0   = VT + (size_t)((b*NH + h)*DH + lr)*SEQ + lg*8;

  // staging geometry: lane l covers row (l>>3), 16B slot (l&7); source pre-swizzled by row&7
  int srow = l >> 3;
  int scol = ((l & 7) ^ srow) * 8;
  auto stageK = [&](int buf, int key0) {
    gld_lds16(Krow0 + (size_t)(key0 + w*16 +     srow)*DIM + scol, Klds + buf*64*64 + (w*16    )*64);
    gld_lds16(Krow0 + (size_t)(key0 + w*16 + 8 + srow)*DIM + scol, Klds + buf*64*64 + (w*16 + 8)*64);
  };

  stageK(0, 0);
  __syncthreads();   // gwl + K[0] ready
  int buf = 0;
  for (int kt = 0; kt < 16; kt++) {
    int key0 = kt*64;
    // ---- issue next-K stage (async DMA, zero VGPR; needed next iter) ----
    if (kt < 15) stageK(buf ^ 1, key0 + 64);
    // ---- force-issue V loads NOW (asm volatile: cannot sink); consumed after softmax ----
    bf16x8 vf[4][2];
#pragma unroll
    for (int dt = 0; dt < 4; dt++) {
      vf[dt][0] = gload16(Vb0 + (size_t)(dt*16)*SEQ + key0);
      vf[dt][1] = gload16(Vb0 + (size_t)(dt*16)*SEQ + key0 + 32);
    }
    // ---- S^T = mfma(K, Q) from LDS (swizzled read): sa[nf][r] = S[key][q=lr] ----
    const unsigned short* Kt = Klds + buf*64*64;
    f32x4 sa[4] = {};
#pragma unroll
    for (int nf = 0; nf < 4; nf++) {
      int r1 = nf*16 + lr;
      int rx = r1 & 7;
      bf16x8 k0 = *(const bf16x8*)&Kt[r1*64 + ((lg       ^ rx) * 8)];
      bf16x8 k1 = *(const bf16x8*)&Kt[r1*64 + (((lg + 4) ^ rx) * 8)];
      sa[nf] = __builtin_amdgcn_mfma_f32_16x16x32_bf16(k0, aq0, sa[nf], 0, 0, 0);
      sa[nf] = __builtin_amdgcn_mfma_f32_16x16x32_bf16(k1, aq1, sa[nf], 0, 0, 0);
    }
    // ---- online softmax in exp2 domain, per-lane scalar state; tree max ----
    float t0 = fmaxf(fmaxf(sa[0][0], sa[0][1]), fmaxf(sa[0][2], sa[0][3]));
    float t1 = fmaxf(fmaxf(sa[1][0], sa[1][1]), fmaxf(sa[1][2], sa[1][3]));
    float t2 = fmaxf(fmaxf(sa[2][0], sa[2][1]), fmaxf(sa[2][2], sa[2][3]));
    float t3 = fmaxf(fmaxf(sa[3][0], sa[3][1]), fmaxf(sa[3][2], sa[3][3]));
    float mx = fmaxf(fmaxf(t0, t1), fmaxf(t2, t3));
    mx = fmaxf(mx, __shfl_xor(mx, 16));
    mx = fmaxf(mx, __shfl_xor(mx, 32));
    float mn = fmaxf(m_, mx);
    float alpha = exp2a(m_ - mn);
    m_ = mn;
    float rsn[4];
    uint32_t u[4][2];
#pragma unroll
    for (int nf = 0; nf < 4; nf++) {
      float4v g = *(const float4v*)&gwl[key0 + nf*16 + lg*4];   // broadcast LDS read
      float p0 = exp2a(sa[nf][0] - m_) * g[0];
      float p1 = exp2a(sa[nf][1] - m_) * g[1];
      float p2 = exp2a(sa[nf][2] - m_) * g[2];
      float p3 = exp2a(sa[nf][3] - m_) * g[3];
      rsn[nf] = (p0 + p1) + (p2 + p3);
      u[nf][0] = cvtpk_bf16(p0, p1);
      u[nf][1] = cvtpk_bf16(p2, p3);
    }
    float rs = (rsn[0] + rsn[1]) + (rsn[2] + rsn[3]);
    rs += __shfl_xor(rs, 16);
    rs += __shfl_xor(rs, 32);
    l_ = l_*alpha + rs;
#pragma unroll
    for (int dt = 0; dt < 4; dt++)
#pragma unroll
      for (int r = 0; r < 4; r++) cacc[dt][r] *= alpha;
    // ---- P[q=lr][key]: 4x ds_write_b64 into wave-local slab ----
#pragma unroll
    for (int nf = 0; nf < 4; nf++) {
      uint32x2 uu; uu[0] = u[nf][0]; uu[1] = u[nf][1];
      *(uint32x2*)&P[w][lr][nf*16 + lg*4] = uu;
    }
    asm volatile("s_waitcnt lgkmcnt(0)" ::: "memory");
    __builtin_amdgcn_sched_barrier(0);
    bf16x8 ap0 = *(const bf16x8*)&P[w][lr][lg*8];        // B-frag: keys 0..31
    bf16x8 ap1 = *(const bf16x8*)&P[w][lr][32 + lg*8];   // B-frag: keys 32..63
    // ---- fence the asm V loads (FIFO: also confirms K[t+1] stage landed) ----
    asm volatile("s_waitcnt vmcnt(0)" ::: "memory");
    __builtin_amdgcn_sched_barrier(0);
    // ---- O^T += mfma(V^T, P) ----
#pragma unroll
    for (int dt = 0; dt < 4; dt++) {
      cacc[dt] = __builtin_amdgcn_mfma_f32_16x16x32_bf16(vf[dt][0], ap0, cacc[dt], 0, 0, 0);
      cacc[dt] = __builtin_amdgcn_mfma_f32_16x16x32_bf16(vf[dt][1], ap1, cacc[dt], 0, 0, 0);
    }
    __syncthreads();   // K dbuf swap: all waves done reading K[t]; stage already drained
    buf ^= 1;
  }

  // ---- epilogue: normalize, pack pairs, 4x b64 stores per lane ----
  float inv = 1.0f / l_;
  size_t row = (size_t)(b*SEQ + q0 + lr)*DIM + h*DH;
#pragma unroll
  for (int dt = 0; dt < 4; dt++) {
    uint32x2 e;
    e[0] = cvtpk_bf16(cacc[dt][0]*inv, cacc[dt][1]*inv);
    e[1] = cvtpk_bf16(cacc[dt][2]*inv, cacc[dt][3]*inv);
    *(uint32x2*)&ctx[row + dt*16 + lg*4] = e;
  }
}

// ---------------- launch ----------------
extern "C" void kernel_launch(void* const* d_in, const int* in_sizes, int n_in,
                              void* d_out, int out_size, void* d_ws, size_t ws_size,
                              hipStream_t stream) {
  const float* query = (const float*)d_in[0];
  const float* key   = (const float*)d_in[1];
  const float* value = (const float*)d_in[2];
  const int*   mask  = (const int*)d_in[3];
  const float* gauss = (const float*)d_in[4];
  const float* Wq = (const float*)d_in[5];
  const float* bq = (const float*)d_in[6];
  const float* Wk = (const float*)d_in[7];
  const float* bk = (const float*)d_in[8];
  const float* Wv = (const float*)d_in[9];
  const float* bv = (const float*)d_in[10];
  const float* Wo = (const float*)d_in[11];
  const float* bo = (const float*)d_in[12];

  char* ws = (char*)d_ws;
  const size_t MB = 1024*1024;
  unsigned short* qb  = (unsigned short*)(ws + 0*MB);   // bf16 casts of inputs (8MB each)
  unsigned short* kb  = (unsigned short*)(ws + 8*MB);
  unsigned short* vb  = (unsigned short*)(ws + 16*MB);
  unsigned short* WqT = (unsigned short*)(ws + 24*MB);  // transposed bf16 weights (2MB each)
  unsigned short* WkT = (unsigned short*)(ws + 26*MB);
  unsigned short* WvT = (unsigned short*)(ws + 28*MB);
  unsigned short* WoT = (unsigned short*)(ws + 30*MB);
  unsigned short* Qp  = (unsigned short*)(ws + 32*MB);  // projected Q (scaled*log2e), natural layout
  unsigned short* Kp  = (unsigned short*)(ws + 40*MB);  // projected K, natural layout
  unsigned short* VTb = (unsigned short*)(ws + 48*MB);  // projected V, [b][h][d][s]
  unsigned short* ctx = (unsigned short*)(ws + 56*MB);  // attention output, natural layout

  cast_qkv<<<dim3((BS*SEQ*DIM)/(256*8), 3), 256, 0, stream>>>(query, key, value, qb, kb, vb);
  wcast_t<<<dim3(DIM/32, DIM/32, 4), 256, 0, stream>>>(Wq, Wk, Wv, Wo, WqT, WkT, WvT, WoT);
  qkv_gemm<<<dim3(NWG, 3), 256, 0, stream>>>(qb, kb, vb, WqT, WkT, WvT, bq, bk, bv, Qp, Kp, VTb);
  attn<<<BS*NH*(SEQ/64), 256, 0, stream>>>(Qp, Kp, VTb, mask, gauss, ctx);
  out_gemm<<<NWG, 256, 0, stream>>>(ctx, WoT, bo, (float*)d_out);
}

// Round 9
// 153.564 us; speedup vs baseline: 1.3205x; 1.0237x over previous
//
#include <hip/hip_runtime.h>
#include <stdint.h>

#define BS 4
#define SEQ 1024
#define DIM 1024
#define NH 16
#define DH 64
#define MROWS (BS*SEQ)   // 4096

#define MT 128
#define NT 128
#define KT 32
#define NBM (MROWS/MT)   // 32
#define NBN (DIM/NT)     // 8
#define NWG (NBM*NBN)    // 256
#define NKT (DIM/KT)     // 32

typedef __attribute__((ext_vector_type(8))) short bf16x8;
typedef __attribute__((ext_vector_type(4))) float f32x4;
typedef __attribute__((ext_vector_type(8))) unsigned short ushort8;
typedef __attribute__((ext_vector_type(4))) float float4v;
typedef __attribute__((ext_vector_type(4))) int int4v;
typedef __attribute__((ext_vector_type(2))) unsigned int uint32x2;

__device__ __forceinline__ unsigned short f2bf(float x) {
  union { float f; uint32_t u; } a; a.f = x;
  uint32_t r = (a.u + 0x7FFFu + ((a.u >> 16) & 1u)) >> 16;  // RNE
  return (unsigned short)r;
}

// packed f32x2 -> bf16x2 (lo = first arg); no builtin on gfx950 -> inline asm (T12)
__device__ __forceinline__ uint32_t cvtpk_bf16(float lo, float hi) {
  uint32_t d;
  asm("v_cvt_pk_bf16_f32 %0, %1, %2" : "=v"(d) : "v"(lo), "v"(hi));
  return d;
}

// raw 2^x (softmax runs in log2 domain; log2e folded into Q scale upstream)
__device__ __forceinline__ float exp2a(float x) {
  float r;
  asm("v_exp_f32 %0, %1" : "=v"(r) : "v"(x));
  return r;
}

// forced-early global load: asm volatile cannot be sunk to its use by the
// scheduler (R4/R5/R7 post-mortems: C-level prefetch ALWAYS sinks at hipcc's
// chosen VGPR target). Consumer must be fenced by counted s_waitcnt vmcnt +
// sched_barrier (rule #18).
__device__ __forceinline__ bf16x8 gload16(const unsigned short* p) {
  bf16x8 r;
  asm volatile("global_load_dwordx4 %0, %1, off" : "=v"(r) : "v"(p));
  return r;
}

typedef const void __attribute__((address_space(1)))* gvp;
typedef void __attribute__((address_space(3)))* lvp;
__device__ __forceinline__ void gld_lds16(const void* g, void* l) {
  // async global->LDS, 16B/lane; LDS dest = wave-uniform base + lane*16
  __builtin_amdgcn_global_load_lds((gvp)g, (lvp)l, 16, 0, 0);
}

// ---------------- fp32 -> bf16 cast (query/key/value) ----------------
__global__ __launch_bounds__(256) void cast_qkv(
    const float* __restrict__ q, const float* __restrict__ k, const float* __restrict__ v,
    unsigned short* __restrict__ qo, unsigned short* __restrict__ ko, unsigned short* __restrict__ vo) {
  const float* s = blockIdx.y == 0 ? q : (blockIdx.y == 1 ? k : v);
  unsigned short* d = blockIdx.y == 0 ? qo : (blockIdx.y == 1 ? ko : vo);
  size_t i = ((size_t)blockIdx.x * 256 + threadIdx.x) * 8;
  float4v x0 = *(const float4v*)(s + i);
  float4v x1 = *(const float4v*)(s + i + 4);
  ushort8 r;
  r[0]=f2bf(x0[0]); r[1]=f2bf(x0[1]); r[2]=f2bf(x0[2]); r[3]=f2bf(x0[3]);
  r[4]=f2bf(x1[0]); r[5]=f2bf(x1[1]); r[6]=f2bf(x1[2]); r[7]=f2bf(x1[3]);
  *(ushort8*)(d + i) = r;
}

// ---------------- weight cast + transpose: WT[n][k] = bf16(W[k][n]) ----------------
__global__ __launch_bounds__(256) void wcast_t(
    const float* __restrict__ w0, const float* __restrict__ w1,
    const float* __restrict__ w2, const float* __restrict__ w3,
    unsigned short* __restrict__ t0, unsigned short* __restrict__ t1,
    unsigned short* __restrict__ t2, unsigned short* __restrict__ t3) {
  __shared__ float tile[32][33];
  const float* W = blockIdx.z == 0 ? w0 : blockIdx.z == 1 ? w1 : blockIdx.z == 2 ? w2 : w3;
  unsigned short* T = blockIdx.z == 0 ? t0 : blockIdx.z == 1 ? t1 : blockIdx.z == 2 ? t2 : t3;
  int tx = threadIdx.x & 31, ty = threadIdx.x >> 5;   // 32 x 8
  int bx = blockIdx.x, by = blockIdx.y;
#pragma unroll
  for (int j = 0; j < 4; j++)
    tile[ty + 8*j][tx] = W[(size_t)(by*32 + ty + 8*j)*DIM + bx*32 + tx];
  __syncthreads();
#pragma unroll
  for (int j = 0; j < 4; j++)
    T[(size_t)(bx*32 + ty + 8*j)*DIM + by*32 + tx] = f2bf(tile[tx][ty + 8*j]);
}

// ---------------- GEMM core: m97-exact 128x128 tile ----------------
// 4 waves (2x2), each computes a 64x64 sub-tile: acc[4][4], 16 MFMA/K-step.
// MODE 0: bf16 out, (acc+bias)*scale; MODE 2: bf16, per-head transposed
// VT[b][h][d][s]; MODE 3: f32 out.
template<int MODE>
__device__ __forceinline__ void gemm_core(
    unsigned short* lds,
    const unsigned short* __restrict__ A, const unsigned short* __restrict__ BT,
    const float* __restrict__ bias, void* __restrict__ outp, float scale) {
  unsigned short* Abase = lds;                 // 2 x MT*KT
  unsigned short* Bbase = lds + 2*MT*KT;       // 2 x NT*KT
  int id = blockIdx.x;
  int sw = (id & 7) * (NWG/8) + (id >> 3);     // XCD swizzle (bijective, 256%8==0)
  int bn = sw & (NBN-1), bm = sw >> 3;         // bn-fast: XCD holds 1MB A-panel + 2MB B (<L2)
  int tid = threadIdx.x, w = tid >> 6, l = tid & 63;
  int wr = w >> 1, wc = w & 1;
  int lr = l & 15, lg = l >> 4;

  auto stage = [&](int buf, int kt) {
    const unsigned short* a0 = A + (size_t)(bm*MT + w*32 + (l>>2))*DIM + kt*KT + (l&3)*8;
    gld_lds16(a0,          Abase + buf*MT*KT + (w*32)*KT);
    gld_lds16(a0 + 16*DIM, Abase + buf*MT*KT + (w*32 + 16)*KT);
    const unsigned short* b0 = BT + (size_t)(bn*NT + w*32 + (l>>2))*DIM + kt*KT + (l&3)*8;
    gld_lds16(b0,          Bbase + buf*NT*KT + (w*32)*KT);
    gld_lds16(b0 + 16*DIM, Bbase + buf*NT*KT + (w*32 + 16)*KT);
  };

  f32x4 acc[4][4] = {};
  int buf = 0;
  stage(0, 0);
  __syncthreads();
  for (int kt = 0; kt < NKT; kt++) {
    if (kt + 1 < NKT) stage(buf ^ 1, kt + 1);
    unsigned short* As = Abase + buf*MT*KT;
    unsigned short* Bs = Bbase + buf*NT*KT;
    bf16x8 af[4], bf_[4];
#pragma unroll
    for (int mi = 0; mi < 4; mi++)
      af[mi] = *(const bf16x8*)&As[(wr*64 + mi*16 + lr)*KT + lg*8];
#pragma unroll
    for (int ni = 0; ni < 4; ni++)
      bf_[ni] = *(const bf16x8*)&Bs[(wc*64 + ni*16 + lr)*KT + lg*8];
#pragma unroll
    for (int mi = 0; mi < 4; mi++)
#pragma unroll
      for (int ni = 0; ni < 4; ni++)
        acc[mi][ni] = __builtin_amdgcn_mfma_f32_16x16x32_bf16(af[mi], bf_[ni], acc[mi][ni], 0, 0, 0);
    __syncthreads();   // drains vmcnt for the staged next tile + protects buffer reuse
    buf ^= 1;
  }

  int row0 = bm*MT + wr*64;
  int col0 = bn*NT + wc*64;
#pragma unroll
  for (int ni = 0; ni < 4; ni++) {
    int col = col0 + ni*16 + lr;
    float bv = bias[col];
#pragma unroll
    for (int mi = 0; mi < 4; mi++)
#pragma unroll
      for (int r = 0; r < 4; r++) {
        int row = row0 + mi*16 + lg*4 + r;
        float val = acc[mi][ni][r] + bv;
        if (MODE == 0) {
          ((unsigned short*)outp)[(size_t)row*DIM + col] = f2bf(val * scale);
        } else if (MODE == 2) {
          int b = row >> 10, s = row & 1023, h = col >> 6, d = col & 63;
          ((unsigned short*)outp)[(size_t)((b*NH + h)*DH + d)*SEQ + s] = f2bf(val);
        } else {
          ((float*)outp)[(size_t)row*DIM + col] = val;
        }
      }
  }
}

__global__ __launch_bounds__(256) void qkv_gemm(
    const unsigned short* __restrict__ qb, const unsigned short* __restrict__ kb,
    const unsigned short* __restrict__ vb,
    const unsigned short* __restrict__ WqT, const unsigned short* __restrict__ WkT,
    const unsigned short* __restrict__ WvT,
    const float* __restrict__ bq, const float* __restrict__ bk, const float* __restrict__ bv,
    unsigned short* __restrict__ Qp, unsigned short* __restrict__ Kp,
    unsigned short* __restrict__ VT) {
  __shared__ __align__(16) unsigned short lds[2*(MT+NT)*KT];
  int z = blockIdx.y;
  // Q scale = 1/sqrt(64) * log2(e): softmax runs in exp2 domain downstream
  if (z == 0)      gemm_core<0>(lds, qb, WqT, bq, Qp, 0.18033688011112042f);
  else if (z == 1) gemm_core<0>(lds, kb, WkT, bk, Kp, 1.0f);
  else             gemm_core<2>(lds, vb, WvT, bv, VT, 1.0f);
}

__global__ __launch_bounds__(256) void out_gemm(
    const unsigned short* __restrict__ ctx, const unsigned short* __restrict__ WoT,
    const float* __restrict__ bo, float* __restrict__ out) {
  __shared__ __align__(16) unsigned short lds[2*(MT+NT)*KT];
  gemm_core<3>(lds, ctx, WoT, bo, out, 1.0f);
}

// ---------------- flash attention (R6 + counted-vmcnt V prefetch) ----------------
// grid 1024, head-major (bh = blk&63): K+V L2-resident per XCD. 4 waves x 16 q-rows.
// Per iter, issue order matters (FIFO vmcnt): (1) 8 V asm-loads for THIS tile,
// (2) 2 K-stage gld_lds for NEXT tile (unconditional, wrapped index -> count is
// loop-invariant). Fence before PV = s_waitcnt vmcnt(2): waits all V, leaves the
// K-stage in flight to be drained by the end-of-iter barrier UNDER PV's MFMA
// (R8 bug: vmcnt(0) pulled the K-stage wait before PV, un-hiding it).
// Swapped QK^T: lane owns q-row lr -> per-lane scalar softmax, 2 shfl per reduce.
// exp2 domain (log2e folded into Q scale): raw v_exp_f32.
__global__ __launch_bounds__(256, 4) void attn(
    const unsigned short* __restrict__ Qp, const unsigned short* __restrict__ Kp,
    const unsigned short* __restrict__ VT, const int* __restrict__ mask,
    const float* __restrict__ gauss, unsigned short* __restrict__ ctx) {
  __shared__ __align__(16) unsigned short Klds[2*64*64];  // 16KB double-buffered K tile
  __shared__ __align__(16) unsigned short P[4][16][72];   // per-wave slab, padded
  __shared__ float gwl[SEQ];                              // mask-folded gauss weights
  int blk = blockIdx.x;
  int bh = blk & 63, qt = blk >> 6;        // head-major: head bh pinned to XCD bh%8
  int b = bh >> 4, h = bh & 15;
  int tid = threadIdx.x, w = tid >> 6, l = tid & 63;
  int lr = l & 15, lg = l >> 4;
  int q0 = qt*64 + w*16;

  // ---- stash mask-folded gauss row in LDS (once) ----
  {
    int i4 = tid * 4;
    float4v g4 = *(const float4v*)(gauss + b*SEQ + i4);
    int4v   m4 = *(const int4v*)(mask + b*SEQ + i4);
#pragma unroll
    for (int j = 0; j < 4; j++) gwl[i4 + j] = m4[j] ? g4[j] + 1e-10f : 0.f;
  }

  const unsigned short* Qb = Qp + (size_t)(b*SEQ + q0 + lr)*DIM + h*DH + lg*8;
  bf16x8 aq0 = *(const bf16x8*)Qb;
  bf16x8 aq1 = *(const bf16x8*)(Qb + 32);

  float m_ = -1e30f, l_ = 0.f;             // per-lane scalars (q = lr)
  f32x4 cacc[4] = {};                      // O^T[d = dt*16+lg*4+r][q = lr]

  const unsigned short* Krow0 = Kp + (size_t)(b*SEQ)*DIM + h*DH;
  const unsigned short* Vb0   = VT + (size_t)((b*NH + h)*DH + lr)*SEQ + lg*8;

  // staging geometry: lane l covers row (l>>3), 16B slot (l&7); source pre-swizzled by row&7
  int srow = l >> 3;
  int scol = ((l & 7) ^ srow) * 8;
  auto stageK = [&](int buf, int key0) {
    gld_lds16(Krow0 + (size_t)(key0 + w*16 +     srow)*DIM + scol, Klds + buf*64*64 + (w*16    )*64);
    gld_lds16(Krow0 + (size_t)(key0 + w*16 + 8 + srow)*DIM + scol, Klds + buf*64*64 + (w*16 + 8)*64);
  };

  stageK(0, 0);
  __syncthreads();   // gwl + K[0] ready
  int buf = 0;
  for (int kt = 0; kt < 16; kt++) {
    int key0 = kt*64;
    // ---- (1) force-issue V loads for THIS tile (asm volatile: cannot sink) ----
    bf16x8 vf[4][2];
#pragma unroll
    for (int dt = 0; dt < 4; dt++) {
      vf[dt][0] = gload16(Vb0 + (size_t)(dt*16)*SEQ + key0);
      vf[dt][1] = gload16(Vb0 + (size_t)(dt*16)*SEQ + key0 + 32);
    }
    // ---- (2) issue next-K stage (async DMA; unconditional so vmcnt count is fixed) ----
    stageK(buf ^ 1, (key0 + 64) & (SEQ-1));
    // ---- S^T = mfma(K, Q) from LDS (swizzled read): sa[nf][r] = S[key][q=lr] ----
    const unsigned short* Kt = Klds + buf*64*64;
    f32x4 sa[4] = {};
#pragma unroll
    for (int nf = 0; nf < 4; nf++) {
      int r1 = nf*16 + lr;
      int rx = r1 & 7;
      bf16x8 k0 = *(const bf16x8*)&Kt[r1*64 + ((lg       ^ rx) * 8)];
      bf16x8 k1 = *(const bf16x8*)&Kt[r1*64 + (((lg + 4) ^ rx) * 8)];
      sa[nf] = __builtin_amdgcn_mfma_f32_16x16x32_bf16(k0, aq0, sa[nf], 0, 0, 0);
      sa[nf] = __builtin_amdgcn_mfma_f32_16x16x32_bf16(k1, aq1, sa[nf], 0, 0, 0);
    }
    // ---- online softmax in exp2 domain, per-lane scalar state; tree max ----
    float t0 = fmaxf(fmaxf(sa[0][0], sa[0][1]), fmaxf(sa[0][2], sa[0][3]));
    float t1 = fmaxf(fmaxf(sa[1][0], sa[1][1]), fmaxf(sa[1][2], sa[1][3]));
    float t2 = fmaxf(fmaxf(sa[2][0], sa[2][1]), fmaxf(sa[2][2], sa[2][3]));
    float t3 = fmaxf(fmaxf(sa[3][0], sa[3][1]), fmaxf(sa[3][2], sa[3][3]));
    float mx = fmaxf(fmaxf(t0, t1), fmaxf(t2, t3));
    mx = fmaxf(mx, __shfl_xor(mx, 16));
    mx = fmaxf(mx, __shfl_xor(mx, 32));
    float mn = fmaxf(m_, mx);
    float alpha = exp2a(m_ - mn);
    m_ = mn;
    float rsn[4];
    uint32_t u[4][2];
#pragma unroll
    for (int nf = 0; nf < 4; nf++) {
      float4v g = *(const float4v*)&gwl[key0 + nf*16 + lg*4];   // broadcast LDS read
      float p0 = exp2a(sa[nf][0] - m_) * g[0];
      float p1 = exp2a(sa[nf][1] - m_) * g[1];
      float p2 = exp2a(sa[nf][2] - m_) * g[2];
      float p3 = exp2a(sa[nf][3] - m_) * g[3];
      rsn[nf] = (p0 + p1) + (p2 + p3);
      u[nf][0] = cvtpk_bf16(p0, p1);
      u[nf][1] = cvtpk_bf16(p2, p3);
    }
    float rs = (rsn[0] + rsn[1]) + (rsn[2] + rsn[3]);
    rs += __shfl_xor(rs, 16);
    rs += __shfl_xor(rs, 32);
    l_ = l_*alpha + rs;
#pragma unroll
    for (int dt = 0; dt < 4; dt++)
#pragma unroll
      for (int r = 0; r < 4; r++) cacc[dt][r] *= alpha;
    // ---- P[q=lr][key]: 4x ds_write_b64 into wave-local slab ----
#pragma unroll
    for (int nf = 0; nf < 4; nf++) {
      uint32x2 uu; uu[0] = u[nf][0]; uu[1] = u[nf][1];
      *(uint32x2*)&P[w][lr][nf*16 + lg*4] = uu;
    }
    asm volatile("s_waitcnt lgkmcnt(0)" ::: "memory");
    __builtin_amdgcn_sched_barrier(0);
    bf16x8 ap0 = *(const bf16x8*)&P[w][lr][lg*8];        // B-frag: keys 0..31
    bf16x8 ap1 = *(const bf16x8*)&P[w][lr][32 + lg*8];   // B-frag: keys 32..63
    // ---- counted fence: all 8 V loads done, 2 K-stage ops stay in flight ----
    asm volatile("s_waitcnt vmcnt(2)" ::: "memory");
    __builtin_amdgcn_sched_barrier(0);
    // ---- O^T += mfma(V^T, P); K-stage drains underneath ----
#pragma unroll
    for (int dt = 0; dt < 4; dt++) {
      cacc[dt] = __builtin_amdgcn_mfma_f32_16x16x32_bf16(vf[dt][0], ap0, cacc[dt], 0, 0, 0);
      cacc[dt] = __builtin_amdgcn_mfma_f32_16x16x32_bf16(vf[dt][1], ap1, cacc[dt], 0, 0, 0);
    }
    __syncthreads();   // K dbuf swap: waves done reading K[t]; stage drained here
    buf ^= 1;
  }

  // ---- epilogue: normalize, pack pairs, 4x b64 stores per lane ----
  float inv = 1.0f / l_;
  size_t row = (size_t)(b*SEQ + q0 + lr)*DIM + h*DH;
#pragma unroll
  for (int dt = 0; dt < 4; dt++) {
    uint32x2 e;
    e[0] = cvtpk_bf16(cacc[dt][0]*inv, cacc[dt][1]*inv);
    e[1] = cvtpk_bf16(cacc[dt][2]*inv, cacc[dt][3]*inv);
    *(uint32x2*)&ctx[row + dt*16 + lg*4] = e;
  }
}

// ---------------- launch ----------------
extern "C" void kernel_launch(void* const* d_in, const int* in_sizes, int n_in,
                              void* d_out, int out_size, void* d_ws, size_t ws_size,
                              hipStream_t stream) {
  const float* query = (const float*)d_in[0];
  const float* key   = (const float*)d_in[1];
  const float* value = (const float*)d_in[2];
  const int*   mask  = (const int*)d_in[3];
  const float* gauss = (const float*)d_in[4];
  const float* Wq = (const float*)d_in[5];
  const float* bq = (const float*)d_in[6];
  const float* Wk = (const float*)d_in[7];
  const float* bk = (const float*)d_in[8];
  const float* Wv = (const float*)d_in[9];
  const float* bv = (const float*)d_in[10];
  const float* Wo = (const float*)d_in[11];
  const float* bo = (const float*)d_in[12];

  char* ws = (char*)d_ws;
  const size_t MB = 1024*1024;
  unsigned short* qb  = (unsigned short*)(ws + 0*MB);   // bf16 casts of inputs (8MB each)
  unsigned short* kb  = (unsigned short*)(ws + 8*MB);
  unsigned short* vb  = (unsigned short*)(ws + 16*MB);
  unsigned short* WqT = (unsigned short*)(ws + 24*MB);  // transposed bf16 weights (2MB each)
  unsigned short* WkT = (unsigned short*)(ws + 26*MB);
  unsigned short* WvT = (unsigned short*)(ws + 28*MB);
  unsigned short* WoT = (unsigned short*)(ws + 30*MB);
  unsigned short* Qp  = (unsigned short*)(ws + 32*MB);  // projected Q (scaled*log2e), natural layout
  unsigned short* Kp  = (unsigned short*)(ws + 40*MB);  // projected K, natural layout
  unsigned short* VTb = (unsigned short*)(ws + 48*MB);  // projected V, [b][h][d][s]
  unsigned short* ctx = (unsigned short*)(ws + 56*MB);  // attention output, natural layout

  cast_qkv<<<dim3((BS*SEQ*DIM)/(256*8), 3), 256, 0, stream>>>(query, key, value, qb, kb, vb);
  wcast_t<<<dim3(DIM/32, DIM/32, 4), 256, 0, stream>>>(Wq, Wk, Wv, Wo, WqT, WkT, WvT, WoT);
  qkv_gemm<<<dim3(NWG, 3), 256, 0, stream>>>(qb, kb, vb, WqT, WkT, WvT, bq, bk, bv, Qp, Kp, VTb);
  attn<<<BS*NH*(SEQ/64), 256, 0, stream>>>(Qp, Kp, VTb, mask, gauss, ctx);
  out_gemm<<<NWG, 256, 0, stream>>>(ctx, WoT, bo, (float*)d_out);
}

// Round 10
// 144.866 us; speedup vs baseline: 1.3998x; 1.0600x over previous
//
#include <hip/hip_runtime.h>
#include <stdint.h>

#define BS 4
#define SEQ 1024
#define DIM 1024
#define NH 16
#define DH 64
#define MROWS (BS*SEQ)   // 4096

#define MT 128
#define NT 128
#define KT 32
#define NBM (MROWS/MT)   // 32
#define NBN (DIM/NT)     // 8
#define NWG (NBM*NBN)    // 256
#define NKT (DIM/KT)     // 32

typedef __attribute__((ext_vector_type(8))) short bf16x8;
typedef __attribute__((ext_vector_type(4))) float f32x4;
typedef __attribute__((ext_vector_type(8))) unsigned short ushort8;
typedef __attribute__((ext_vector_type(4))) float float4v;
typedef __attribute__((ext_vector_type(4))) int int4v;
typedef __attribute__((ext_vector_type(2))) unsigned int uint32x2;

__device__ __forceinline__ unsigned short f2bf(float x) {
  union { float f; uint32_t u; } a; a.f = x;
  uint32_t r = (a.u + 0x7FFFu + ((a.u >> 16) & 1u)) >> 16;  // RNE
  return (unsigned short)r;
}

// packed f32x2 -> bf16x2 (lo = first arg); no builtin on gfx950 -> inline asm (T12)
__device__ __forceinline__ uint32_t cvtpk_bf16(float lo, float hi) {
  uint32_t d;
  asm("v_cvt_pk_bf16_f32 %0, %1, %2" : "=v"(d) : "v"(lo), "v"(hi));
  return d;
}

// raw 2^x (softmax runs in log2 domain; log2e folded into Q scale upstream)
__device__ __forceinline__ float exp2a(float x) {
  float r;
  asm("v_exp_f32 %0, %1" : "=v"(r) : "v"(x));
  return r;
}

typedef const void __attribute__((address_space(1)))* gvp;
typedef void __attribute__((address_space(3)))* lvp;
__device__ __forceinline__ void gld_lds16(const void* g, void* l) {
  // async global->LDS, 16B/lane; LDS dest = wave-uniform base + lane*16
  __builtin_amdgcn_global_load_lds((gvp)g, (lvp)l, 16, 0, 0);
}

// ---------------- fp32 -> bf16 cast (query/key/value) ----------------
__global__ __launch_bounds__(256) void cast_qkv(
    const float* __restrict__ q, const float* __restrict__ k, const float* __restrict__ v,
    unsigned short* __restrict__ qo, unsigned short* __restrict__ ko, unsigned short* __restrict__ vo) {
  const float* s = blockIdx.y == 0 ? q : (blockIdx.y == 1 ? k : v);
  unsigned short* d = blockIdx.y == 0 ? qo : (blockIdx.y == 1 ? ko : vo);
  size_t i = ((size_t)blockIdx.x * 256 + threadIdx.x) * 8;
  float4v x0 = *(const float4v*)(s + i);
  float4v x1 = *(const float4v*)(s + i + 4);
  ushort8 r;
  r[0]=f2bf(x0[0]); r[1]=f2bf(x0[1]); r[2]=f2bf(x0[2]); r[3]=f2bf(x0[3]);
  r[4]=f2bf(x1[0]); r[5]=f2bf(x1[1]); r[6]=f2bf(x1[2]); r[7]=f2bf(x1[3]);
  *(ushort8*)(d + i) = r;
}

// ---------------- weight cast + transpose: WT[n][k] = bf16(W[k][n]) ----------------
__global__ __launch_bounds__(256) void wcast_t(
    const float* __restrict__ w0, const float* __restrict__ w1,
    const float* __restrict__ w2, const float* __restrict__ w3,
    unsigned short* __restrict__ t0, unsigned short* __restrict__ t1,
    unsigned short* __restrict__ t2, unsigned short* __restrict__ t3) {
  __shared__ float tile[32][33];
  const float* W = blockIdx.z == 0 ? w0 : blockIdx.z == 1 ? w1 : blockIdx.z == 2 ? w2 : w3;
  unsigned short* T = blockIdx.z == 0 ? t0 : blockIdx.z == 1 ? t1 : blockIdx.z == 2 ? t2 : t3;
  int tx = threadIdx.x & 31, ty = threadIdx.x >> 5;   // 32 x 8
  int bx = blockIdx.x, by = blockIdx.y;
#pragma unroll
  for (int j = 0; j < 4; j++)
    tile[ty + 8*j][tx] = W[(size_t)(by*32 + ty + 8*j)*DIM + bx*32 + tx];
  __syncthreads();
#pragma unroll
  for (int j = 0; j < 4; j++)
    T[(size_t)(bx*32 + ty + 8*j)*DIM + by*32 + tx] = f2bf(tile[tx][ty + 8*j]);
}

// ---------------- GEMM core: m97-exact 128x128 tile ----------------
// 4 waves (2x2), each computes a 64x64 sub-tile: acc[4][4], 16 MFMA/K-step.
// MODE 0: bf16 out, (acc+bias)*scale; MODE 2: bf16, per-head transposed
// VT[b][h][d][s]; MODE 3: f32 out.
template<int MODE>
__device__ __forceinline__ void gemm_core(
    unsigned short* lds,
    const unsigned short* __restrict__ A, const unsigned short* __restrict__ BT,
    const float* __restrict__ bias, void* __restrict__ outp, float scale) {
  unsigned short* Abase = lds;                 // 2 x MT*KT
  unsigned short* Bbase = lds + 2*MT*KT;       // 2 x NT*KT
  int id = blockIdx.x;
  int sw = (id & 7) * (NWG/8) + (id >> 3);     // XCD swizzle (bijective, 256%8==0)
  int bn = sw & (NBN-1), bm = sw >> 3;         // bn-fast: XCD holds 1MB A-panel + 2MB B (<L2)
  int tid = threadIdx.x, w = tid >> 6, l = tid & 63;
  int wr = w >> 1, wc = w & 1;
  int lr = l & 15, lg = l >> 4;

  auto stage = [&](int buf, int kt) {
    const unsigned short* a0 = A + (size_t)(bm*MT + w*32 + (l>>2))*DIM + kt*KT + (l&3)*8;
    gld_lds16(a0,          Abase + buf*MT*KT + (w*32)*KT);
    gld_lds16(a0 + 16*DIM, Abase + buf*MT*KT + (w*32 + 16)*KT);
    const unsigned short* b0 = BT + (size_t)(bn*NT + w*32 + (l>>2))*DIM + kt*KT + (l&3)*8;
    gld_lds16(b0,          Bbase + buf*NT*KT + (w*32)*KT);
    gld_lds16(b0 + 16*DIM, Bbase + buf*NT*KT + (w*32 + 16)*KT);
  };

  f32x4 acc[4][4] = {};
  int buf = 0;
  stage(0, 0);
  __syncthreads();
  for (int kt = 0; kt < NKT; kt++) {
    if (kt + 1 < NKT) stage(buf ^ 1, kt + 1);
    unsigned short* As = Abase + buf*MT*KT;
    unsigned short* Bs = Bbase + buf*NT*KT;
    bf16x8 af[4], bf_[4];
#pragma unroll
    for (int mi = 0; mi < 4; mi++)
      af[mi] = *(const bf16x8*)&As[(wr*64 + mi*16 + lr)*KT + lg*8];
#pragma unroll
    for (int ni = 0; ni < 4; ni++)
      bf_[ni] = *(const bf16x8*)&Bs[(wc*64 + ni*16 + lr)*KT + lg*8];
#pragma unroll
    for (int mi = 0; mi < 4; mi++)
#pragma unroll
      for (int ni = 0; ni < 4; ni++)
        acc[mi][ni] = __builtin_amdgcn_mfma_f32_16x16x32_bf16(af[mi], bf_[ni], acc[mi][ni], 0, 0, 0);
    __syncthreads();   // drains vmcnt for the staged next tile + protects buffer reuse
    buf ^= 1;
  }

  int row0 = bm*MT + wr*64;
  int col0 = bn*NT + wc*64;
#pragma unroll
  for (int ni = 0; ni < 4; ni++) {
    int col = col0 + ni*16 + lr;
    float bv = bias[col];
#pragma unroll
    for (int mi = 0; mi < 4; mi++)
#pragma unroll
      for (int r = 0; r < 4; r++) {
        int row = row0 + mi*16 + lg*4 + r;
        float val = acc[mi][ni][r] + bv;
        if (MODE == 0) {
          ((unsigned short*)outp)[(size_t)row*DIM + col] = f2bf(val * scale);
        } else if (MODE == 2) {
          int b = row >> 10, s = row & 1023, h = col >> 6, d = col & 63;
          ((unsigned short*)outp)[(size_t)((b*NH + h)*DH + d)*SEQ + s] = f2bf(val);
        } else {
          ((float*)outp)[(size_t)row*DIM + col] = val;
        }
      }
  }
}

__global__ __launch_bounds__(256) void qkv_gemm(
    const unsigned short* __restrict__ qb, const unsigned short* __restrict__ kb,
    const unsigned short* __restrict__ vb,
    const unsigned short* __restrict__ WqT, const unsigned short* __restrict__ WkT,
    const unsigned short* __restrict__ WvT,
    const float* __restrict__ bq, const float* __restrict__ bk, const float* __restrict__ bv,
    unsigned short* __restrict__ Qp, unsigned short* __restrict__ Kp,
    unsigned short* __restrict__ VT) {
  __shared__ __align__(16) unsigned short lds[2*(MT+NT)*KT];
  int z = blockIdx.y;
  // Q scale = 1/sqrt(64) * log2(e): softmax runs in exp2 domain downstream
  if (z == 0)      gemm_core<0>(lds, qb, WqT, bq, Qp, 0.18033688011112042f);
  else if (z == 1) gemm_core<0>(lds, kb, WkT, bk, Kp, 1.0f);
  else             gemm_core<2>(lds, vb, WvT, bv, VT, 1.0f);
}

__global__ __launch_bounds__(256) void out_gemm(
    const unsigned short* __restrict__ ctx, const unsigned short* __restrict__ WoT,
    const float* __restrict__ bo, float* __restrict__ out) {
  __shared__ __align__(16) unsigned short lds[2*(MT+NT)*KT];
  gemm_core<3>(lds, ctx, WoT, bo, out, 1.0f);
}

// ---------------- flash attention (R6-exact schedule + exp2 + defer-max) ----------------
// grid 1024, head-major (bh = blk&63): K+V L2-resident per XCD. 4 waves x 16 q-rows.
// K: async global_load_lds double-buffer (zero-VGPR prefetch; the ONLY prefetch
// scheme that beats hipcc's default schedule - R4/R5/R7/R8/R9 all confirmed
// register-prefetch forcing loses). XOR-swizzled LDS layout. V: plain C loads,
// compiler-scheduled (R6=72us vs forced-early R8/R9=77/80us).
// Swapped QK^T: lane owns q-row lr -> per-lane scalar softmax, 2 shfl per reduce.
// exp2 domain (log2e folded into Q scale). T13 defer-max: skip alpha-rescale
// when max growth <= 8 (P bounded by 2^8; f32/bf16 safe).
__global__ __launch_bounds__(256, 4) void attn(
    const unsigned short* __restrict__ Qp, const unsigned short* __restrict__ Kp,
    const unsigned short* __restrict__ VT, const int* __restrict__ mask,
    const float* __restrict__ gauss, unsigned short* __restrict__ ctx) {
  __shared__ __align__(16) unsigned short Klds[2*64*64];  // 16KB double-buffered K tile
  __shared__ __align__(16) unsigned short P[4][16][72];   // per-wave slab, padded
  __shared__ float gwl[SEQ];                              // mask-folded gauss weights
  int blk = blockIdx.x;
  int bh = blk & 63, qt = blk >> 6;        // head-major: head bh pinned to XCD bh%8
  int b = bh >> 4, h = bh & 15;
  int tid = threadIdx.x, w = tid >> 6, l = tid & 63;
  int lr = l & 15, lg = l >> 4;
  int q0 = qt*64 + w*16;

  // ---- stash mask-folded gauss row in LDS (once) ----
  {
    int i4 = tid * 4;
    float4v g4 = *(const float4v*)(gauss + b*SEQ + i4);
    int4v   m4 = *(const int4v*)(mask + b*SEQ + i4);
#pragma unroll
    for (int j = 0; j < 4; j++) gwl[i4 + j] = m4[j] ? g4[j] + 1e-10f : 0.f;
  }

  const unsigned short* Qb = Qp + (size_t)(b*SEQ + q0 + lr)*DIM + h*DH + lg*8;
  bf16x8 aq0 = *(const bf16x8*)Qb;
  bf16x8 aq1 = *(const bf16x8*)(Qb + 32);

  float m_ = -1e30f, l_ = 0.f;             // per-lane scalars (q = lr)
  f32x4 cacc[4] = {};                      // O^T[d = dt*16+lg*4+r][q = lr]

  const unsigned short* Krow0 = Kp + (size_t)(b*SEQ)*DIM + h*DH;
  const unsigned short* Vb0   = VT + (size_t)((b*NH + h)*DH + lr)*SEQ + lg*8;

  // staging geometry: lane l covers row (l>>3), 16B slot (l&7); source pre-swizzled by row&7
  int srow = l >> 3;
  int scol = ((l & 7) ^ srow) * 8;
  auto stageK = [&](int buf, int key0) {
    gld_lds16(Krow0 + (size_t)(key0 + w*16 +     srow)*DIM + scol, Klds + buf*64*64 + (w*16    )*64);
    gld_lds16(Krow0 + (size_t)(key0 + w*16 + 8 + srow)*DIM + scol, Klds + buf*64*64 + (w*16 + 8)*64);
  };

  stageK(0, 0);
  __syncthreads();   // gwl + K[0] ready
  int buf = 0;
  for (int kt = 0; kt < 16; kt++) {
    int key0 = kt*64;
    // ---- issue next-K stage (async DMA, zero VGPR; drained by end-of-iter barrier) ----
    if (kt < 15) stageK(buf ^ 1, key0 + 64);
    // ---- S^T = mfma(K, Q) from LDS (swizzled read): sa[nf][r] = S[key][q=lr] ----
    const unsigned short* Kt = Klds + buf*64*64;
    f32x4 sa[4] = {};
#pragma unroll
    for (int nf = 0; nf < 4; nf++) {
      int r1 = nf*16 + lr;
      int rx = r1 & 7;
      bf16x8 k0 = *(const bf16x8*)&Kt[r1*64 + ((lg       ^ rx) * 8)];
      bf16x8 k1 = *(const bf16x8*)&Kt[r1*64 + (((lg + 4) ^ rx) * 8)];
      sa[nf] = __builtin_amdgcn_mfma_f32_16x16x32_bf16(k0, aq0, sa[nf], 0, 0, 0);
      sa[nf] = __builtin_amdgcn_mfma_f32_16x16x32_bf16(k1, aq1, sa[nf], 0, 0, 0);
    }
    // ---- V loads (plain; compiler-scheduled - beats every forcing scheme tried) ----
    bf16x8 vf[4][2];
#pragma unroll
    for (int dt = 0; dt < 4; dt++) {
      vf[dt][0] = *(const bf16x8*)(Vb0 + (size_t)(dt*16)*SEQ + key0);
      vf[dt][1] = *(const bf16x8*)(Vb0 + (size_t)(dt*16)*SEQ + key0 + 32);
    }
    // ---- online softmax in exp2 domain; tree max; T13 defer-max ----
    float t0 = fmaxf(fmaxf(sa[0][0], sa[0][1]), fmaxf(sa[0][2], sa[0][3]));
    float t1 = fmaxf(fmaxf(sa[1][0], sa[1][1]), fmaxf(sa[1][2], sa[1][3]));
    float t2 = fmaxf(fmaxf(sa[2][0], sa[2][1]), fmaxf(sa[2][2], sa[2][3]));
    float t3 = fmaxf(fmaxf(sa[3][0], sa[3][1]), fmaxf(sa[3][2], sa[3][3]));
    float mx = fmaxf(fmaxf(t0, t1), fmaxf(t2, t3));
    mx = fmaxf(mx, __shfl_xor(mx, 16));
    mx = fmaxf(mx, __shfl_xor(mx, 32));
    if (!__all(mx - m_ <= 8.0f)) {         // rescale only on real max growth
      float mn = fmaxf(m_, mx);
      float alpha = exp2a(m_ - mn);
      m_ = mn;
      l_ *= alpha;
#pragma unroll
      for (int dt = 0; dt < 4; dt++)
#pragma unroll
        for (int r = 0; r < 4; r++) cacc[dt][r] *= alpha;
    }
    float rsn[4];
    uint32_t u[4][2];
#pragma unroll
    for (int nf = 0; nf < 4; nf++) {
      float4v g = *(const float4v*)&gwl[key0 + nf*16 + lg*4];   // broadcast LDS read
      float p0 = exp2a(sa[nf][0] - m_) * g[0];
      float p1 = exp2a(sa[nf][1] - m_) * g[1];
      float p2 = exp2a(sa[nf][2] - m_) * g[2];
      float p3 = exp2a(sa[nf][3] - m_) * g[3];
      rsn[nf] = (p0 + p1) + (p2 + p3);
      u[nf][0] = cvtpk_bf16(p0, p1);
      u[nf][1] = cvtpk_bf16(p2, p3);
    }
    float rs = (rsn[0] + rsn[1]) + (rsn[2] + rsn[3]);
    rs += __shfl_xor(rs, 16);
    rs += __shfl_xor(rs, 32);
    l_ += rs;
    // ---- P[q=lr][key]: 4x ds_write_b64 into wave-local slab ----
#pragma unroll
    for (int nf = 0; nf < 4; nf++) {
      uint32x2 uu; uu[0] = u[nf][0]; uu[1] = u[nf][1];
      *(uint32x2*)&P[w][lr][nf*16 + lg*4] = uu;
    }
    asm volatile("s_waitcnt lgkmcnt(0)" ::: "memory");
    __builtin_amdgcn_sched_barrier(0);
    bf16x8 ap0 = *(const bf16x8*)&P[w][lr][lg*8];        // B-frag: keys 0..31
    bf16x8 ap1 = *(const bf16x8*)&P[w][lr][32 + lg*8];   // B-frag: keys 32..63
    // ---- O^T += mfma(V^T, P) ----
#pragma unroll
    for (int dt = 0; dt < 4; dt++) {
      cacc[dt] = __builtin_amdgcn_mfma_f32_16x16x32_bf16(vf[dt][0], ap0, cacc[dt], 0, 0, 0);
      cacc[dt] = __builtin_amdgcn_mfma_f32_16x16x32_bf16(vf[dt][1], ap1, cacc[dt], 0, 0, 0);
    }
    __syncthreads();   // K dbuf swap: waves done reading K[t]; next-K stage drains here
    buf ^= 1;
  }

  // ---- epilogue: normalize, pack pairs, 4x b64 stores per lane ----
  float inv = 1.0f / l_;
  size_t row = (size_t)(b*SEQ + q0 + lr)*DIM + h*DH;
#pragma unroll
  for (int dt = 0; dt < 4; dt++) {
    uint32x2 e;
    e[0] = cvtpk_bf16(cacc[dt][0]*inv, cacc[dt][1]*inv);
    e[1] = cvtpk_bf16(cacc[dt][2]*inv, cacc[dt][3]*inv);
    *(uint32x2*)&ctx[row + dt*16 + lg*4] = e;
  }
}

// ---------------- launch ----------------
extern "C" void kernel_launch(void* const* d_in, const int* in_sizes, int n_in,
                              void* d_out, int out_size, void* d_ws, size_t ws_size,
                              hipStream_t stream) {
  const float* query = (const float*)d_in[0];
  const float* key   = (const float*)d_in[1];
  const float* value = (const float*)d_in[2];
  const int*   mask  = (const int*)d_in[3];
  const float* gauss = (const float*)d_in[4];
  const float* Wq = (const float*)d_in[5];
  const float* bq = (const float*)d_in[6];
  const float* Wk = (const float*)d_in[7];
  const float* bk = (const float*)d_in[8];
  const float* Wv = (const float*)d_in[9];
  const float* bv = (const float*)d_in[10];
  const float* Wo = (const float*)d_in[11];
  const float* bo = (const float*)d_in[12];

  char* ws = (char*)d_ws;
  const size_t MB = 1024*1024;
  unsigned short* qb  = (unsigned short*)(ws + 0*MB);   // bf16 casts of inputs (8MB each)
  unsigned short* kb  = (unsigned short*)(ws + 8*MB);
  unsigned short* vb  = (unsigned short*)(ws + 16*MB);
  unsigned short* WqT = (unsigned short*)(ws + 24*MB);  // transposed bf16 weights (2MB each)
  unsigned short* WkT = (unsigned short*)(ws + 26*MB);
  unsigned short* WvT = (unsigned short*)(ws + 28*MB);
  unsigned short* WoT = (unsigned short*)(ws + 30*MB);
  unsigned short* Qp  = (unsigned short*)(ws + 32*MB);  // projected Q (scaled*log2e), natural layout
  unsigned short* Kp  = (unsigned short*)(ws + 40*MB);  // projected K, natural layout
  unsigned short* VTb = (unsigned short*)(ws + 48*MB);  // projected V, [b][h][d][s]
  unsigned short* ctx = (unsigned short*)(ws + 56*MB);  // attention output, natural layout

  cast_qkv<<<dim3((BS*SEQ*DIM)/(256*8), 3), 256, 0, stream>>>(query, key, value, qb, kb, vb);
  wcast_t<<<dim3(DIM/32, DIM/32, 4), 256, 0, stream>>>(Wq, Wk, Wv, Wo, WqT, WkT, WvT, WoT);
  qkv_gemm<<<dim3(NWG, 3), 256, 0, stream>>>(qb, kb, vb, WqT, WkT, WvT, bq, bk, bv, Qp, Kp, VTb);
  attn<<<BS*NH*(SEQ/64), 256, 0, stream>>>(Qp, Kp, VTb, mask, gauss, ctx);
  out_gemm<<<NWG, 256, 0, stream>>>(ctx, WoT, bo, (float*)d_out);
}